// Round 1
// baseline (117.768 us; speedup 1.0000x reference)
//
#include <hip/hip_runtime.h>

#define BATCH_N 65536
#define SEQ_N   128

// One thread per batch element; 128-step sequential recurrence in-registers.
// Software prefetch pipeline depth 8 (single rotating buffer: copy to x, then
// immediately re-issue the load for t+8 into the same slot) to hide HBM
// latency at 1 wave/SIMD occupancy.
__global__ __launch_bounds__(256) void fsrs_kernel(
    const float2* __restrict__ in,   // (SEQ, BATCH) of (t, rating)
    const float*  __restrict__ w,    // 17 weights
    float2*       __restrict__ out)  // (SEQ, BATCH) of (s, d) then (BATCH) final
{
    const int b = blockIdx.x * 256 + threadIdx.x;

    // Uniform weight loads (land in SGPRs).
    const float w0 = w[0], w1 = w[1], w2 = w[2], w3 = w[3];
    const float w4 = w[4], w5 = w[5], w6 = w[6], w7 = w[7];
    const float w9 = w[9], w11 = w[11], w12 = w[12], w13 = w[13];
    const float w15 = w[15], w16 = w[16];
    constexpr float LOG2E = 1.44269504088896340736f;
    const float expw8 = __builtin_amdgcn_exp2f(w[8] * LOG2E);  // exp(w8)
    const float w10l  = w[10] * LOG2E;   // exp(x*w10) = exp2(x*w10l)
    const float w14l  = w[14] * LOG2E;
    const float w7w4  = w7 * w4;
    const float omw7  = 1.0f - w7;

    const float2* ip = in  + b;   // stride BATCH_N per timestep
    float2*       op = out + b;

    float s = 0.01f, d = 1.0f;

    // One FSRS recurrence step (t >= 1). Reads old (s,d), writes new (s,d).
    auto step = [&](float2 x) {
        const float tt     = x.x;
        const float rating = x.y;
        const float nineS = 9.0f * s;
        // r = 1/(1 + t/(9s)) == 9s/(9s + t)
        const float r   = nineS * __builtin_amdgcn_rcpf(nineS + tt);
        const float omr = 1.0f - r;
        const float hp  = (rating == 2.0f) ? w15 : 1.0f;
        const float eb  = (rating == 4.0f) ? w16 : 1.0f;
        // s^(-w9) ; exp((1-r)*w10)
        const float pows  = __builtin_amdgcn_exp2f(-w9 * __builtin_amdgcn_logf(s));
        const float e10   = __builtin_amdgcn_exp2f(omr * w10l);
        const float s_succ = s * (1.0f + expw8 * (11.0f - d) * pows *
                                  (e10 - 1.0f) * hp * eb);
        // d^(-w12) ; (s+1)^w13 ; exp((1-r)*w14)
        const float powd  = __builtin_amdgcn_exp2f(-w12 * __builtin_amdgcn_logf(d));
        const float pows1 = __builtin_amdgcn_exp2f( w13 * __builtin_amdgcn_logf(s + 1.0f));
        const float e14   = __builtin_amdgcn_exp2f(omr * w14l);
        const float s_fail = fminf(w11 * powd * (pows1 - 1.0f) * e14, s);

        const float ns = (rating > 1.0f) ? s_succ : s_fail;
        float nd = d - w6 * (rating - 3.0f);
        nd = w7w4 + omw7 * nd;
        d = fminf(fmaxf(nd, 1.0f), 10.0f);
        s = fminf(fmaxf(ns, 0.01f), 36500.0f);
    };

    // Prologue: load t=0..7.
    float2 A[8];
#pragma unroll
    for (int i = 0; i < 8; ++i) A[i] = ip[i * BATCH_N];

    // Chunk 0: t=0 is the special first step; prefetch t=8..15 as we go.
    {
        float2 x = A[0];
        A[0] = ip[8 * BATCH_N];
        const float rating = x.y;
        int ri = (int)rating - 1;
        ri = ri < 0 ? 0 : (ri > 3 ? 3 : ri);
        const float wsel = (ri < 2) ? (ri == 0 ? w0 : w1)
                                    : (ri == 2 ? w2 : w3);
        const float ns = (rating >= 1.0f && rating <= 4.0f) ? wsel : 1.0f;
        const float nd = w4 - w5 * (rating - 3.0f);
        d = fminf(fmaxf(nd, 1.0f), 10.0f);
        s = fminf(fmaxf(ns, 0.01f), 36500.0f);
        op[0] = make_float2(s, d);
    }
#pragma unroll
    for (int i = 1; i < 8; ++i) {
        float2 x = A[i];
        A[i] = ip[(8 + i) * BATCH_N];
        step(x);
        op[i * BATCH_N] = make_float2(s, d);
    }

    // Chunks 1..15: 8 steps each, prefetch next chunk into the same slots.
    // Keep rolled: fully unrolling 15x blows I-cache.
#pragma unroll 1
    for (int c = 1; c < 16; ++c) {
#pragma unroll
        for (int i = 0; i < 8; ++i) {
            float2 x = A[i];
            int tpf = c * 8 + 8 + i;
            tpf = tpf > 127 ? 127 : tpf;   // clamp: last chunk re-loads row 127 (harmless, L2-hit)
            A[i] = ip[tpf * BATCH_N];
            step(x);
            op[(c * 8 + i) * BATCH_N] = make_float2(s, d);
        }
    }

    // final_state, appended after the (SEQ, BATCH) outputs.
    op[SEQ_N * BATCH_N] = make_float2(s, d);
}

extern "C" void kernel_launch(void* const* d_in, const int* in_sizes, int n_in,
                              void* d_out, int out_size, void* d_ws, size_t ws_size,
                              hipStream_t stream) {
    const float2* in = (const float2*)d_in[0];   // (128, 65536, 2) f32
    const float*  w  = (const float*)d_in[1];    // (17,) f32
    float2* out = (float2*)d_out;                // 128*65536 + 65536 float2
    fsrs_kernel<<<BATCH_N / 256, 256, 0, stream>>>(in, w, out);
}